// Round 1
// baseline (263.109 us; speedup 1.0000x reference)
//
#include <hip/hip_runtime.h>

// PointPillars BEV scatter — gather formulation.
// Output layout: (B, C, H, W) fp32. H*W = 214272 = 837 * 256 exactly.

#define BEV_H 496
#define BEV_W 432
#define BB 4
#define CC 64
#define HW (BEV_H * BEV_W)      // 214272
#define HW_BLOCKS (HW / 256)    // 837 (exact)

// Step 2: scatter pillar index m into the (B,H,W) map. Map pre-set to -1.
__global__ __launch_bounds__(256) void scatter_idx_kernel(
    const int* __restrict__ coords, int* __restrict__ map, int M) {
  int m = blockIdx.x * 256 + threadIdx.x;
  if (m >= M) return;
  int b = coords[3 * m + 0];
  int y = coords[3 * m + 1];
  int x = coords[3 * m + 2];
  map[(b * BEV_H + y) * BEV_W + x] = m;
}

// Step 3: each block owns 256 contiguous hw positions of one batch.
// Each thread reads its map entry once, then writes all 64 channel planes.
// Per plane a wave stores 256 contiguous bytes -> output written exactly
// once, fully coalesced, zeroing fused (branchless select for empty cells).
__global__ __launch_bounds__(256) void gather_kernel(
    const int* __restrict__ map, const float4* __restrict__ feat4,
    float* __restrict__ out) {
  int blk = blockIdx.x;
  int b = blk / HW_BLOCKS;
  int hw = (blk - b * HW_BLOCKS) * 256 + threadIdx.x;

  int m = map[b * HW + hw];
  const bool empty = (m < 0);
  int mm = empty ? 0 : m;  // empty lanes read row 0 (broadcast, L1 hit)

  float* o = out + (size_t)b * CC * HW + hw;
  const float4* fr = feat4 + (size_t)mm * (CC / 4);

#pragma unroll
  for (int c4 = 0; c4 < CC / 4; ++c4) {
    float4 v = fr[c4];
    if (empty) { v.x = 0.f; v.y = 0.f; v.z = 0.f; v.w = 0.f; }
    o[(size_t)(4 * c4 + 0) * HW] = v.x;
    o[(size_t)(4 * c4 + 1) * HW] = v.y;
    o[(size_t)(4 * c4 + 2) * HW] = v.z;
    o[(size_t)(4 * c4 + 3) * HW] = v.w;
  }
}

extern "C" void kernel_launch(void* const* d_in, const int* in_sizes, int n_in,
                              void* d_out, int out_size, void* d_ws, size_t ws_size,
                              hipStream_t stream) {
  const int*   coords = (const int*)d_in[0];    // (M, 3) int32
  const float* feat   = (const float*)d_in[1];  // (M, 64) fp32
  float*       out    = (float*)d_out;          // (4, 64, 496, 432) fp32
  int M = in_sizes[0] / 3;

  int* map = (int*)d_ws;  // (B, H, W) int32 index map, 3.43 MB

  // Step 1: map = -1 everywhere (0xFF bytes). Stream-ordered, graph-safe.
  hipMemsetAsync(map, 0xFF, (size_t)BB * HW * sizeof(int), stream);

  scatter_idx_kernel<<<(M + 255) / 256, 256, 0, stream>>>(coords, map, M);

  gather_kernel<<<BB * HW_BLOCKS, 256, 0, stream>>>(
      map, (const float4*)feat, out);
}

// Round 2
// 257.174 us; speedup vs baseline: 1.0231x; 1.0231x over previous
//
#include <hip/hip_runtime.h>

// PointPillars BEV scatter — gather formulation, float4-vectorized stores.
// Output layout: (B, C, H, W) fp32. B*H*W = 857088 = 4 * 214272; 214272/256 = 837.

#define BEV_H 496
#define BEV_W 432
#define BB 4
#define CC 64
#define HW (BEV_H * BEV_W)          // 214272 (divisible by 4 and 256)
#define NQUAD (BB * HW / 4)         // 214272 quad-cells over the whole (B,H,W) map
#define QBLOCKS (NQUAD / 256)       // 837 (exact)

// Step 2: scatter pillar index m into the (B,H,W) map. Map pre-set to -1.
__global__ __launch_bounds__(256) void scatter_idx_kernel(
    const int* __restrict__ coords, int* __restrict__ map, int M) {
  int m = blockIdx.x * 256 + threadIdx.x;
  if (m >= M) return;
  int b = coords[3 * m + 0];
  int y = coords[3 * m + 1];
  int x = coords[3 * m + 2];
  map[(b * BEV_H + y) * BEV_W + x] = m;
}

// Step 3: each thread owns 4 contiguous hw cells (one int4 map read).
// For each block of 4 channels: load float4 from each of the 4 feature rows,
// transpose 4x4 in registers, store one float4 per channel plane.
// Per wave-instruction: 1 KB contiguous store. Output written exactly once.
__global__ __launch_bounds__(256) void gather4_kernel(
    const int4* __restrict__ map4, const float4* __restrict__ feat4,
    float4* __restrict__ out4) {
  int q = blockIdx.x * 256 + threadIdx.x;       // quad-cell index in [0, NQUAD)
  int cell = q * 4;                              // flat (b*HW + hw)
  int b = cell / HW;
  int hw0 = cell - b * HW;                       // multiple of 4

  int4 mi = map4[q];
  int m0 = mi.x, m1 = mi.y, m2 = mi.z, m3 = mi.w;
  bool e0 = m0 < 0, e1 = m1 < 0, e2 = m2 < 0, e3 = m3 < 0;
  const float4* r0 = feat4 + (size_t)(e0 ? 0 : m0) * (CC / 4);
  const float4* r1 = feat4 + (size_t)(e1 ? 0 : m1) * (CC / 4);
  const float4* r2 = feat4 + (size_t)(e2 ? 0 : m2) * (CC / 4);
  const float4* r3 = feat4 + (size_t)(e3 ? 0 : m3) * (CC / 4);

  // out float4 index for (b, c, hw0): (b*CC + c)*HW/4 + hw0/4
  size_t obase = (size_t)b * CC * (HW / 4) + (hw0 >> 2);

#pragma unroll
  for (int c4 = 0; c4 < CC / 4; ++c4) {
    float4 a0 = r0[c4];
    float4 a1 = r1[c4];
    float4 a2 = r2[c4];
    float4 a3 = r3[c4];
    if (e0) a0 = make_float4(0.f, 0.f, 0.f, 0.f);
    if (e1) a1 = make_float4(0.f, 0.f, 0.f, 0.f);
    if (e2) a2 = make_float4(0.f, 0.f, 0.f, 0.f);
    if (e3) a3 = make_float4(0.f, 0.f, 0.f, 0.f);
    // channel c = 4*c4 + k gets lane-values (a0[k], a1[k], a2[k], a3[k])
    out4[obase + (size_t)(4 * c4 + 0) * (HW / 4)] = make_float4(a0.x, a1.x, a2.x, a3.x);
    out4[obase + (size_t)(4 * c4 + 1) * (HW / 4)] = make_float4(a0.y, a1.y, a2.y, a3.y);
    out4[obase + (size_t)(4 * c4 + 2) * (HW / 4)] = make_float4(a0.z, a1.z, a2.z, a3.z);
    out4[obase + (size_t)(4 * c4 + 3) * (HW / 4)] = make_float4(a0.w, a1.w, a2.w, a3.w);
  }
}

extern "C" void kernel_launch(void* const* d_in, const int* in_sizes, int n_in,
                              void* d_out, int out_size, void* d_ws, size_t ws_size,
                              hipStream_t stream) {
  const int*   coords = (const int*)d_in[0];    // (M, 3) int32
  const float* feat   = (const float*)d_in[1];  // (M, 64) fp32
  float*       out    = (float*)d_out;          // (4, 64, 496, 432) fp32
  int M = in_sizes[0] / 3;

  int* map = (int*)d_ws;  // (B, H, W) int32 index map, 3.43 MB

  // Step 1: map = -1 everywhere (0xFF bytes). Stream-ordered, graph-safe.
  hipMemsetAsync(map, 0xFF, (size_t)BB * HW * sizeof(int), stream);

  scatter_idx_kernel<<<(M + 255) / 256, 256, 0, stream>>>(coords, map, M);

  gather4_kernel<<<QBLOCKS, 256, 0, stream>>>(
      (const int4*)map, (const float4*)feat, (float4*)out);
}